// Round 1
// baseline (196.081 us; speedup 1.0000x reference)
//
#include <hip/hip_runtime.h>

#define BB 32
#define HH 256
#define WW 256
#define HW (HH*WW)
#define KP1 9
#define KNEG 8
#define MARGIN_F 10.0f
#define RATIO_INV_F 10000.0f

// ws accumulator layout (floats):
// [0..31]    sum_pos[b]
// [32+s*32+b]  corner_sum[s][b]
// [96+s*32+b]  co_sum[s][b]
// [160+s*32+b] bo_sum[s][b]
// total 224 floats

__device__ __forceinline__ float fast_tanh(float x) {
    float xc = fminf(fmaxf(x, -15.f), 15.f);
    float t = __expf(2.f * xc);
    return (t - 1.f) / (t + 1.f);
}
__device__ __forceinline__ float fast_sigmoid(float x) {
    return 1.f / (1.f + __expf(-x));
}
__device__ __forceinline__ float smooth_l1(float d) {
    float ad = fabsf(d);
    return ad < 1.f ? 0.5f * d * d : ad - 0.5f;
}

__global__ __launch_bounds__(256) void ml_reduce_kernel(
    const float* __restrict__ out0, const float* __restrict__ out1,
    const float* __restrict__ t_corner, const float* __restrict__ t_co,
    const float* __restrict__ t_bin, float* __restrict__ acc)
{
    const int PIX_PER_BLOCK = 2048;              // 8 iters of 256 threads
    const int blocks_per_b = HW / PIX_PER_BLOCK; // 32
    const int b = blockIdx.x / blocks_per_b;
    const int chunk = blockIdx.x % blocks_per_b;
    const int base = chunk * PIX_PER_BLOCK;

    const float* tc  = t_corner + (size_t)b * HW;
    const float* tco = t_co     + (size_t)b * 2 * HW;
    const float* tb  = t_bin    + (size_t)b * 2 * HW;
    const float* o0  = out0 + (size_t)b * 7 * HW;
    const float* o1  = out1 + (size_t)b * 7 * HW;

    float s_pos = 0.f;
    float s_corner0 = 0.f, s_corner1 = 0.f;
    float s_co0 = 0.f, s_co1 = 0.f;
    float s_bo0 = 0.f, s_bo1 = 0.f;

    for (int it = 0; it < PIX_PER_BLOCK / 256; ++it) {
        const int p = base + it * 256 + threadIdx.x;
        const float pos  = tc[p];
        s_pos += pos;
        const float tgt0 = tco[p], tgt1 = tco[HW + p];
        const float m0 = (tgt0 != 0.f) ? RATIO_INV_F : 1.f;
        const float m1 = (tgt1 != 0.f) ? RATIO_INV_F : 1.f;
        const float tb0 = tb[p], tb1 = tb[HW + p];

        // ---- stack 0 ----
        {
            const float c0 = o0[HW + p], c1 = o0[2 * HW + p];
            const float mx = fmaxf(c0, c1);
            const float lse = mx + __logf(1.f + __expf(-fabsf(c0 - c1)));
            const float nl0 = lse - c0, nl1 = lse - c1;
            s_corner0 += pos * nl1 * RATIO_INV_F + (1.f - pos) * nl0;

            const float co0 = fast_tanh(o0[3 * HW + p]) * (float)HH;
            const float co1 = fast_tanh(o0[4 * HW + p]) * (float)WW;
            s_co0 += m0 * smooth_l1(co0 - tgt0) + m1 * smooth_l1(co1 - tgt1);

            const float sb0 = fabsf(fast_sigmoid(o0[5 * HW + p]) - 0.5f - tb0);
            const float sb1 = fabsf(fast_sigmoid(o0[6 * HW + p]) - 0.5f - tb1);
            s_bo0 += (sb0 + sb1) * pos;
        }
        // ---- stack 1 ----
        {
            const float c0 = o1[HW + p], c1 = o1[2 * HW + p];
            const float mx = fmaxf(c0, c1);
            const float lse = mx + __logf(1.f + __expf(-fabsf(c0 - c1)));
            const float nl0 = lse - c0, nl1 = lse - c1;
            s_corner1 += pos * nl1 * RATIO_INV_F + (1.f - pos) * nl0;

            const float co0 = fast_tanh(o1[3 * HW + p]) * (float)HH;
            const float co1 = fast_tanh(o1[4 * HW + p]) * (float)WW;
            s_co1 += m0 * smooth_l1(co0 - tgt0) + m1 * smooth_l1(co1 - tgt1);

            const float sb0 = fabsf(fast_sigmoid(o1[5 * HW + p]) - 0.5f - tb0);
            const float sb1 = fabsf(fast_sigmoid(o1[6 * HW + p]) - 0.5f - tb1);
            s_bo1 += (sb0 + sb1) * pos;
        }
    }

    // block-level reduction of 7 partials, then atomicAdd
    __shared__ float part[7][4];
    const int lane = threadIdx.x & 63;
    const int wid  = threadIdx.x >> 6;
    float vals[7] = { s_pos, s_corner0, s_corner1, s_co0, s_co1, s_bo0, s_bo1 };
#pragma unroll
    for (int v = 0; v < 7; ++v) {
        float x = vals[v];
#pragma unroll
        for (int off = 32; off; off >>= 1) x += __shfl_down(x, off);
        if (lane == 0) part[v][wid] = x;
    }
    __syncthreads();
    if (threadIdx.x < 7) {
        const int v = threadIdx.x;
        float x = part[v][0] + part[v][1] + part[v][2] + part[v][3];
        atomicAdd(&acc[v * 32 + b], x);
    }
}

__global__ __launch_bounds__(256) void ml_final_kernel(
    const float* __restrict__ out0, const float* __restrict__ out1,
    const int* __restrict__ anchors, const int* __restrict__ positives,
    const int* __restrict__ neg_zero, const int* __restrict__ neg_other,
    const float* __restrict__ acc, float* __restrict__ out)
{
    __shared__ float lc[2];
    __shared__ float red[2][4];

    float local0 = 0.f, local1 = 0.f;
    for (int i = threadIdx.x; i < 2 * BB * KP1; i += blockDim.x) {
        const int s = i / (BB * KP1);
        const int r = i % (BB * KP1);
        const int b = r / KP1, c = r % KP1;
        const float* o = (s ? out1 : out0) + (size_t)b * 7 * HW; // channel 0 base
        const int ia  = anchors  [b * KP1 + c];
        const int ip  = positives[b * KP1 + c];
        const int in1 = neg_zero [b * KP1 + c];
        const float va = o[ia], vp = o[ip], vn1 = o[in1];
        const float Dap = (va - vp) * (va - vp);
        const float h1 = fmaxf(0.f, Dap - (va - vn1) * (va - vn1) + MARGIN_F);
        float pc;
        if (c > 0) {
            const int in2 = neg_other[b * KNEG + (c - 1)];
            const float vn2 = o[in2];
            const float h2 = fmaxf(0.f, Dap - (va - vn2) * (va - vn2) + MARGIN_F);
            pc = 0.5f * (h1 + h2);
        } else {
            pc = h1;
        }
        if (s == 0) local0 += pc; else local1 += pc;
    }

    const int lane = threadIdx.x & 63;
    const int wid  = threadIdx.x >> 6;
    {
        float x = local0;
#pragma unroll
        for (int off = 32; off; off >>= 1) x += __shfl_down(x, off);
        if (lane == 0) red[0][wid] = x;
    }
    {
        float x = local1;
#pragma unroll
        for (int off = 32; off; off >>= 1) x += __shfl_down(x, off);
        if (lane == 0) red[1][wid] = x;
    }
    __syncthreads();
    if (threadIdx.x < 2) {
        lc[threadIdx.x] = (red[threadIdx.x][0] + red[threadIdx.x][1] +
                           red[threadIdx.x][2] + red[threadIdx.x][3]) /
                          (float)(KP1 * BB);
    }
    __syncthreads();

    const float invHW = 1.f / (float)HW;
    for (int i = threadIdx.x; i < 2 * 97; i += blockDim.x) {
        const int s = i / 97, j = i % 97;
        float val;
        if (j == 0) {
            val = lc[s]; // LW center = 1.0
        } else if (j < 33) {
            const int b = j - 1;
            val = acc[32 + s * 32 + b] * invHW;            // l_corner, LW 1.0
        } else if (j < 65) {
            const int b = j - 33;
            val = 0.25f * acc[96 + s * 32 + b] * invHW;    // l_co, LW 0.25
        } else {
            const int b = j - 65;
            const float sp = acc[b];
            // l_bo = bo_sum/(HW*w), w = sp/HW if sp!=0 else 1  => bo_sum/sp or bo_sum/HW
            val = (sp > 0.f) ? (acc[160 + s * 32 + b] / sp)
                             : (acc[160 + s * 32 + b] * invHW);
        }
        out[i] = val;
    }
}

extern "C" void kernel_launch(void* const* d_in, const int* in_sizes, int n_in,
                              void* d_out, int out_size, void* d_ws, size_t ws_size,
                              hipStream_t stream) {
    const float* out0      = (const float*)d_in[0];
    const float* out1      = (const float*)d_in[1];
    const float* t_corner  = (const float*)d_in[2];
    const float* t_co      = (const float*)d_in[3];
    const float* t_bin     = (const float*)d_in[4];
    const int*   anchors   = (const int*)d_in[5];
    const int*   positives = (const int*)d_in[6];
    const int*   neg_zero  = (const int*)d_in[7];
    const int*   neg_other = (const int*)d_in[8];
    float* acc = (float*)d_ws;
    float* out = (float*)d_out;

    hipMemsetAsync(acc, 0, 224 * sizeof(float), stream);

    const int PIX_PER_BLOCK = 2048;
    dim3 grid(BB * (HW / PIX_PER_BLOCK)); // 32 * 32 = 1024 blocks
    ml_reduce_kernel<<<grid, 256, 0, stream>>>(out0, out1, t_corner, t_co, t_bin, acc);
    ml_final_kernel<<<1, 256, 0, stream>>>(out0, out1, anchors, positives, neg_zero,
                                           neg_other, acc, out);
}

// Round 2
// 191.563 us; speedup vs baseline: 1.0236x; 1.0236x over previous
//
#include <hip/hip_runtime.h>

#define BB 32
#define HH 256
#define WW 256
#define HW (HH*WW)
#define HW4 (HW/4)
#define KP1 9
#define KNEG 8
#define MARGIN_F 10.0f
#define RATIO_INV_F 10000.0f

// ws accumulator layout (floats):
// [0..31]      sum_pos[b]
// [32+s*32+b]  corner_sum[s][b]
// [96+s*32+b]  co_sum[s][b]
// [160+s*32+b] bo_sum[s][b]
// total 224 floats

__device__ __forceinline__ float fast_tanh(float x) {
    float xc = fminf(fmaxf(x, -15.f), 15.f);
    float t = __expf(2.f * xc);
    return (t - 1.f) / (t + 1.f);
}
__device__ __forceinline__ float fast_sigmoid(float x) {
    return 1.f / (1.f + __expf(-x));
}
__device__ __forceinline__ float smooth_l1(float d) {
    float ad = fabsf(d);
    return ad < 1.f ? 0.5f * d * d : ad - 0.5f;
}
__device__ __forceinline__ float el(const float4& v, int j) {
    return reinterpret_cast<const float*>(&v)[j];
}

// 2048 blocks x 256 threads x 4 pixels/thread (float4), 64 blocks per batch.
__global__ __launch_bounds__(256) void ml_reduce_kernel(
    const float* __restrict__ out0, const float* __restrict__ out1,
    const float* __restrict__ t_corner, const float* __restrict__ t_co,
    const float* __restrict__ t_bin, float* __restrict__ acc)
{
    const int b = blockIdx.x >> 6;       // 64 blocks per batch
    const int chunk = blockIdx.x & 63;
    const int i4 = chunk * 256 + threadIdx.x;   // float4 index within HW4

    const float4* tc4  = (const float4*)(t_corner + (size_t)b * HW);
    const float4* tco4 = (const float4*)(t_co     + (size_t)b * 2 * HW);
    const float4* tb4  = (const float4*)(t_bin    + (size_t)b * 2 * HW);
    const float4* o04  = (const float4*)(out0 + (size_t)b * 7 * HW);
    const float4* o14  = (const float4*)(out1 + (size_t)b * 7 * HW);

    // Issue all loads up front (17 independent float4 loads -> deep MLP)
    const float4 pv   = tc4[i4];
    const float4 tg0  = tco4[i4];
    const float4 tg1  = tco4[HW4 + i4];
    const float4 tbv0 = tb4[i4];
    const float4 tbv1 = tb4[HW4 + i4];
    const float4 a0c1 = o04[1 * HW4 + i4];
    const float4 a0c2 = o04[2 * HW4 + i4];
    const float4 a0c3 = o04[3 * HW4 + i4];
    const float4 a0c4 = o04[4 * HW4 + i4];
    const float4 a0c5 = o04[5 * HW4 + i4];
    const float4 a0c6 = o04[6 * HW4 + i4];
    const float4 a1c1 = o14[1 * HW4 + i4];
    const float4 a1c2 = o14[2 * HW4 + i4];
    const float4 a1c3 = o14[3 * HW4 + i4];
    const float4 a1c4 = o14[4 * HW4 + i4];
    const float4 a1c5 = o14[5 * HW4 + i4];
    const float4 a1c6 = o14[6 * HW4 + i4];

    float s_pos = 0.f;
    float s_corner0 = 0.f, s_corner1 = 0.f;
    float s_co0 = 0.f, s_co1 = 0.f;
    float s_bo0 = 0.f, s_bo1 = 0.f;

#pragma unroll
    for (int j = 0; j < 4; ++j) {
        const float pos = el(pv, j);
        s_pos += pos;
        const float tgt0 = el(tg0, j), tgt1 = el(tg1, j);
        const float m0 = (tgt0 != 0.f) ? RATIO_INV_F : 1.f;
        const float m1 = (tgt1 != 0.f) ? RATIO_INV_F : 1.f;
        const float tb0 = el(tbv0, j), tb1 = el(tbv1, j);

        // ---- stack 0 ----
        {
            const float c0 = el(a0c1, j), c1 = el(a0c2, j);
            const float mx = fmaxf(c0, c1);
            const float lse = mx + __logf(1.f + __expf(-fabsf(c0 - c1)));
            s_corner0 += pos * (lse - c1) * RATIO_INV_F + (1.f - pos) * (lse - c0);

            const float co0 = fast_tanh(el(a0c3, j)) * (float)HH;
            const float co1 = fast_tanh(el(a0c4, j)) * (float)WW;
            s_co0 += m0 * smooth_l1(co0 - tgt0) + m1 * smooth_l1(co1 - tgt1);

            const float sb0 = fabsf(fast_sigmoid(el(a0c5, j)) - 0.5f - tb0);
            const float sb1 = fabsf(fast_sigmoid(el(a0c6, j)) - 0.5f - tb1);
            s_bo0 += (sb0 + sb1) * pos;
        }
        // ---- stack 1 ----
        {
            const float c0 = el(a1c1, j), c1 = el(a1c2, j);
            const float mx = fmaxf(c0, c1);
            const float lse = mx + __logf(1.f + __expf(-fabsf(c0 - c1)));
            s_corner1 += pos * (lse - c1) * RATIO_INV_F + (1.f - pos) * (lse - c0);

            const float co0 = fast_tanh(el(a1c3, j)) * (float)HH;
            const float co1 = fast_tanh(el(a1c4, j)) * (float)WW;
            s_co1 += m0 * smooth_l1(co0 - tgt0) + m1 * smooth_l1(co1 - tgt1);

            const float sb0 = fabsf(fast_sigmoid(el(a1c5, j)) - 0.5f - tb0);
            const float sb1 = fabsf(fast_sigmoid(el(a1c6, j)) - 0.5f - tb1);
            s_bo1 += (sb0 + sb1) * pos;
        }
    }

    // block-level reduction of 7 partials, then atomicAdd
    __shared__ float part[7][4];
    const int lane = threadIdx.x & 63;
    const int wid  = threadIdx.x >> 6;
    float vals[7] = { s_pos, s_corner0, s_corner1, s_co0, s_co1, s_bo0, s_bo1 };
#pragma unroll
    for (int v = 0; v < 7; ++v) {
        float x = vals[v];
#pragma unroll
        for (int off = 32; off; off >>= 1) x += __shfl_down(x, off);
        if (lane == 0) part[v][wid] = x;
    }
    __syncthreads();
    if (threadIdx.x < 7) {
        const int v = threadIdx.x;
        float x = part[v][0] + part[v][1] + part[v][2] + part[v][3];
        atomicAdd(&acc[v * 32 + b], x);
    }
}

__global__ __launch_bounds__(256) void ml_final_kernel(
    const float* __restrict__ out0, const float* __restrict__ out1,
    const int* __restrict__ anchors, const int* __restrict__ positives,
    const int* __restrict__ neg_zero, const int* __restrict__ neg_other,
    const float* __restrict__ acc, float* __restrict__ out)
{
    __shared__ float lc[2];
    __shared__ float red[2][4];

    float local0 = 0.f, local1 = 0.f;
    for (int i = threadIdx.x; i < 2 * BB * KP1; i += blockDim.x) {
        const int s = i / (BB * KP1);
        const int r = i % (BB * KP1);
        const int b = r / KP1, c = r % KP1;
        const float* o = (s ? out1 : out0) + (size_t)b * 7 * HW; // channel 0 base
        const int ia  = anchors  [b * KP1 + c];
        const int ip  = positives[b * KP1 + c];
        const int in1 = neg_zero [b * KP1 + c];
        const float va = o[ia], vp = o[ip], vn1 = o[in1];
        const float Dap = (va - vp) * (va - vp);
        const float h1 = fmaxf(0.f, Dap - (va - vn1) * (va - vn1) + MARGIN_F);
        float pc;
        if (c > 0) {
            const int in2 = neg_other[b * KNEG + (c - 1)];
            const float vn2 = o[in2];
            const float h2 = fmaxf(0.f, Dap - (va - vn2) * (va - vn2) + MARGIN_F);
            pc = 0.5f * (h1 + h2);
        } else {
            pc = h1;
        }
        if (s == 0) local0 += pc; else local1 += pc;
    }

    const int lane = threadIdx.x & 63;
    const int wid  = threadIdx.x >> 6;
    {
        float x = local0;
#pragma unroll
        for (int off = 32; off; off >>= 1) x += __shfl_down(x, off);
        if (lane == 0) red[0][wid] = x;
    }
    {
        float x = local1;
#pragma unroll
        for (int off = 32; off; off >>= 1) x += __shfl_down(x, off);
        if (lane == 0) red[1][wid] = x;
    }
    __syncthreads();
    if (threadIdx.x < 2) {
        lc[threadIdx.x] = (red[threadIdx.x][0] + red[threadIdx.x][1] +
                           red[threadIdx.x][2] + red[threadIdx.x][3]) /
                          (float)(KP1 * BB);
    }
    __syncthreads();

    const float invHW = 1.f / (float)HW;
    for (int i = threadIdx.x; i < 2 * 97; i += blockDim.x) {
        const int s = i / 97, j = i % 97;
        float val;
        if (j == 0) {
            val = lc[s]; // LW center = 1.0
        } else if (j < 33) {
            const int b = j - 1;
            val = acc[32 + s * 32 + b] * invHW;            // l_corner, LW 1.0
        } else if (j < 65) {
            const int b = j - 33;
            val = 0.25f * acc[96 + s * 32 + b] * invHW;    // l_co, LW 0.25
        } else {
            const int b = j - 65;
            const float sp = acc[b];
            // l_bo = bo_sum/(HW*w), w = sp/HW if sp!=0 else 1 => bo_sum/sp or bo_sum/HW
            val = (sp > 0.f) ? (acc[160 + s * 32 + b] / sp)
                             : (acc[160 + s * 32 + b] * invHW);
        }
        out[i] = val;
    }
}

extern "C" void kernel_launch(void* const* d_in, const int* in_sizes, int n_in,
                              void* d_out, int out_size, void* d_ws, size_t ws_size,
                              hipStream_t stream) {
    const float* out0      = (const float*)d_in[0];
    const float* out1      = (const float*)d_in[1];
    const float* t_corner  = (const float*)d_in[2];
    const float* t_co      = (const float*)d_in[3];
    const float* t_bin     = (const float*)d_in[4];
    const int*   anchors   = (const int*)d_in[5];
    const int*   positives = (const int*)d_in[6];
    const int*   neg_zero  = (const int*)d_in[7];
    const int*   neg_other = (const int*)d_in[8];
    float* acc = (float*)d_ws;
    float* out = (float*)d_out;

    hipMemsetAsync(acc, 0, 224 * sizeof(float), stream);

    dim3 grid(BB * 64); // 2048 blocks, 1024 pixels each
    ml_reduce_kernel<<<grid, 256, 0, stream>>>(out0, out1, t_corner, t_co, t_bin, acc);
    ml_final_kernel<<<1, 256, 0, stream>>>(out0, out1, anchors, positives, neg_zero,
                                           neg_other, acc, out);
}